// Round 2
// baseline (411.709 us; speedup 1.0000x reference)
//
#include <hip/hip_runtime.h>
#include <math.h>

#define BB 16
#define II 1024
#define HH 2048

__device__ __forceinline__ float gumbel_xf(float u) {
    // -log(-log(u + 1e-10) + 1e-10)
    float l1 = __logf(u + 1e-10f);
    return -__logf(-l1 + 1e-10f);
}

// One wave (64 lanes) handles one (b, o) row of length H=2048, single pass.
// No softmax max-shift: z = W*mask/tau + gumbel, gumbel <= -log(2^-24) ~ 16.6,
// |W/tau| <= ~0.12  =>  exp(z) <= ~2e7, row sum <= ~1e9 -- safe in fp32.
// Block = 256 threads = 4 waves = 4 consecutive b's for one o.
// Block swizzle: n = 32q + 8g + c  ->  o = 8q + c, batch-group g.
// Same-o blocks differ only by stride 8 in n -> same XCD (n%8), L2 reuse of W_hh row.
__global__ __launch_bounds__(256, 4) void reservoir_cell_kernel(
    const float* __restrict__ x_t,        // (B, I)
    const float* __restrict__ h_prev,     // (B, H)
    const float* __restrict__ W_ih_w,     // (H, I)
    const float* __restrict__ W_ih_b,     // (H,)
    const float* __restrict__ W_hh,       // (H, H)
    const float* __restrict__ hh_mask,    // (H, H)
    const float* __restrict__ temperature,// (1,)
    const float* __restrict__ gumbel,     // (B, H, H)
    float* __restrict__ out)              // (B, H)
{
    const int n    = blockIdx.x;               // 0..8191
    const int o    = ((n >> 5) << 3) + (n & 7);// 0..2047
    const int grp  = (n >> 3) & 3;             // 0..3
    const int wave = threadIdx.x >> 6;         // 0..3
    const int lane = threadIdx.x & 63;
    const int b    = (grp << 2) + wave;        // 0..15

    const float tau     = fmaxf(temperature[0], 1e-3f);
    const float inv_tau = 1.0f / tau;

    // ---- input contribution: dot(x_t[b,:], W_ih_w[o,:]) ----
    const float4* x4 = (const float4*)(x_t + (size_t)b * II);
    const float4* w4 = (const float4*)(W_ih_w + (size_t)o * II);
    float ic = 0.0f;
    #pragma unroll
    for (int j = 0; j < 4; ++j) {
        float4 xv = x4[j * 64 + lane];
        float4 wv = w4[j * 64 + lane];
        ic += xv.x * wv.x + xv.y * wv.y + xv.z * wv.z + xv.w * wv.w;
    }

    // ---- single streaming pass:
    //      z = W*mask/tau + gumbel(u);  e = exp(z);  s += e;  t += e*h_prev ----
    const float4* g4 = (const float4*)(gumbel + ((size_t)b * HH + o) * HH);
    const float4* h4 = (const float4*)(W_hh   + (size_t)o * HH);
    const float4* m4 = (const float4*)(hh_mask+ (size_t)o * HH);
    const float4* p4 = (const float4*)(h_prev + (size_t)b * HH);

    float s = 0.0f, t = 0.0f;
    #pragma unroll 4
    for (int j = 0; j < 8; ++j) {
        float4 u  = g4[j * 64 + lane];
        float4 w  = h4[j * 64 + lane];
        float4 mk = m4[j * 64 + lane];
        float4 hv = p4[j * 64 + lane];
        float e;
        e = __expf(w.x * mk.x * inv_tau + gumbel_xf(u.x)); s += e; t += e * hv.x;
        e = __expf(w.y * mk.y * inv_tau + gumbel_xf(u.y)); s += e; t += e * hv.y;
        e = __expf(w.z * mk.z * inv_tau + gumbel_xf(u.z)); s += e; t += e * hv.z;
        e = __expf(w.w * mk.w * inv_tau + gumbel_xf(u.w)); s += e; t += e * hv.w;
    }

    // ---- wave reductions (ic, s, t) ----
    #pragma unroll
    for (int off = 32; off; off >>= 1) {
        ic += __shfl_down(ic, off, 64);
        s  += __shfl_down(s,  off, 64);
        t  += __shfl_down(t,  off, 64);
    }

    if (lane == 0) {
        out[(size_t)b * HH + o] = tanhf(ic + W_ih_b[o] + t / s);
    }
}

extern "C" void kernel_launch(void* const* d_in, const int* in_sizes, int n_in,
                              void* d_out, int out_size, void* d_ws, size_t ws_size,
                              hipStream_t stream) {
    const float* x_t         = (const float*)d_in[0];
    const float* h_prev      = (const float*)d_in[1];
    const float* W_ih_w      = (const float*)d_in[2];
    const float* W_ih_b      = (const float*)d_in[3];
    const float* W_hh        = (const float*)d_in[4];
    const float* hh_mask     = (const float*)d_in[5];
    const float* temperature = (const float*)d_in[6];
    const float* gumbel      = (const float*)d_in[7];
    float* out = (float*)d_out;

    // B*H rows, 1 wave per row, 4 waves per block -> 16*2048/4 = 8192 blocks
    dim3 grid(8192), block(256);
    reservoir_cell_kernel<<<grid, block, 0, stream>>>(
        x_t, h_prev, W_ih_w, W_ih_b, W_hh, hh_mask, temperature, gumbel, out);
}

// Round 3
// 408.858 us; speedup vs baseline: 1.0070x; 1.0070x over previous
//
#include <hip/hip_runtime.h>
#include <math.h>

#define BB 16
#define II 1024
#define HH 2048

// ---------------------------------------------------------------------------
// Pass 1: Q[o,h] = exp(W_hh[o,h] * hh_mask[o,h] / tau)   (batch-invariant)
// 2048*2048 floats = 16.8 MB into d_ws. ~50 MB traffic, ~8 us.
// ---------------------------------------------------------------------------
__global__ __launch_bounds__(256) void precompute_q_kernel(
    const float* __restrict__ W_hh,
    const float* __restrict__ hh_mask,
    const float* __restrict__ temperature,
    float* __restrict__ Q)
{
    const float tau = fmaxf(temperature[0], 1e-3f);
    const float inv_tau = 1.0f / tau;
    const int idx = blockIdx.x * blockDim.x + threadIdx.x;  // float4 index
    float4 w  = ((const float4*)W_hh)[idx];
    float4 mk = ((const float4*)hh_mask)[idx];
    float4 q;
    q.x = __expf(w.x * mk.x * inv_tau);
    q.y = __expf(w.y * mk.y * inv_tau);
    q.z = __expf(w.z * mk.z * inv_tau);
    q.w = __expf(w.w * mk.w * inv_tau);
    ((float4*)Q)[idx] = q;
}

// ---------------------------------------------------------------------------
// Pass 2: one wave per (b,o) row. exp(gumbel(u)) = 1/L with L = eps - log(u+eps),
// so e = Q/L -- no exp in the hot loop, 2 trans (log, rcp) + ~4 VALU per elem.
// No softmax max-shift needed: Q in [0.89, 1.13], 1/L <= ~1e8, row sum < 1e9
// -- safe in fp32; the shift cancels in t/s anyway.
// Block = 256 = 4 waves = 4 batches for one o. Swizzle keeps same-o blocks on
// one XCD (n%8 = o%8) so Q/W_ih rows are per-XCD L2-resident (~3 MB/XCD).
// ---------------------------------------------------------------------------
__global__ __launch_bounds__(256, 4) void reservoir_cell_kernel(
    const float* __restrict__ x_t,        // (B, I)
    const float* __restrict__ h_prev,     // (B, H)
    const float* __restrict__ W_ih_w,     // (H, I)
    const float* __restrict__ W_ih_b,     // (H,)
    const float* __restrict__ Q,          // (H, H) precomputed
    const float* __restrict__ gumbel,     // (B, H, H)
    float* __restrict__ out)              // (B, H)
{
    const int n    = blockIdx.x;               // 0..8191
    const int o    = ((n >> 5) << 3) + (n & 7);// 0..2047
    const int grp  = (n >> 3) & 3;             // 0..3
    const int wave = threadIdx.x >> 6;         // 0..3
    const int lane = threadIdx.x & 63;
    const int b    = (grp << 2) + wave;        // 0..15

    // ---- input contribution: dot(x_t[b,:], W_ih_w[o,:]) ----
    const float4* x4 = (const float4*)(x_t + (size_t)b * II);
    const float4* w4 = (const float4*)(W_ih_w + (size_t)o * II);
    float ic = 0.0f;
    #pragma unroll
    for (int j = 0; j < 4; ++j) {
        float4 xv = x4[j * 64 + lane];
        float4 wv = w4[j * 64 + lane];
        ic += xv.x * wv.x + xv.y * wv.y + xv.z * wv.z + xv.w * wv.w;
    }

    // ---- streaming pass: L = eps - log(u+eps); e = Q/L; s += e; t += e*h ----
    const float4* g4 = (const float4*)(gumbel + ((size_t)b * HH + o) * HH);
    const float4* q4 = (const float4*)(Q      + (size_t)o * HH);
    const float4* p4 = (const float4*)(h_prev + (size_t)b * HH);

    float s = 0.0f, t = 0.0f;
    #pragma unroll 4
    for (int j = 0; j < 8; ++j) {
        float4 u  = g4[j * 64 + lane];
        float4 qv = q4[j * 64 + lane];
        float4 hv = p4[j * 64 + lane];
        float L, e;
        L = 1e-10f - __logf(u.x + 1e-10f); e = qv.x * __builtin_amdgcn_rcpf(L); s += e; t += e * hv.x;
        L = 1e-10f - __logf(u.y + 1e-10f); e = qv.y * __builtin_amdgcn_rcpf(L); s += e; t += e * hv.y;
        L = 1e-10f - __logf(u.z + 1e-10f); e = qv.z * __builtin_amdgcn_rcpf(L); s += e; t += e * hv.z;
        L = 1e-10f - __logf(u.w + 1e-10f); e = qv.w * __builtin_amdgcn_rcpf(L); s += e; t += e * hv.w;
    }

    // ---- wave reductions (ic, s, t) ----
    #pragma unroll
    for (int off = 32; off; off >>= 1) {
        ic += __shfl_down(ic, off, 64);
        s  += __shfl_down(s,  off, 64);
        t  += __shfl_down(t,  off, 64);
    }

    if (lane == 0) {
        out[(size_t)b * HH + o] = tanhf(ic + W_ih_b[o] + t / s);
    }
}

extern "C" void kernel_launch(void* const* d_in, const int* in_sizes, int n_in,
                              void* d_out, int out_size, void* d_ws, size_t ws_size,
                              hipStream_t stream) {
    const float* x_t         = (const float*)d_in[0];
    const float* h_prev      = (const float*)d_in[1];
    const float* W_ih_w      = (const float*)d_in[2];
    const float* W_ih_b      = (const float*)d_in[3];
    const float* W_hh        = (const float*)d_in[4];
    const float* hh_mask     = (const float*)d_in[5];
    const float* temperature = (const float*)d_in[6];
    const float* gumbel      = (const float*)d_in[7];
    float* out = (float*)d_out;
    float* Q   = (float*)d_ws;  // 2048*2048 floats = 16.8 MB, ws is plenty

    // Pass 1: 4M elements / 4 per thread / 256 per block = 4096 blocks
    precompute_q_kernel<<<dim3(HH * HH / 4 / 256), dim3(256), 0, stream>>>(
        W_hh, hh_mask, temperature, Q);

    // Pass 2: B*H rows, 1 wave per row, 4 waves per block -> 8192 blocks
    reservoir_cell_kernel<<<dim3(8192), dim3(256), 0, stream>>>(
        x_t, h_prev, W_ih_w, W_ih_b, Q, gumbel, out);
}